// Round 12
// baseline (519.238 us; speedup 1.0000x reference)
//
#include <hip/hip_runtime.h>
#include <hip/hip_fp16.h>

#define WAVE 64

constexpr int D_IN = 128;
constexpr int F1 = 64;
constexpr int F2 = 128;
constexpr int NG = 64;
constexpr float NEG = 0.2f;
constexpr int NBLK1 = 512;       // level-1 binning blocks

using f16x8 = __attribute__((ext_vector_type(8))) _Float16;
using f32x4 = __attribute__((ext_vector_type(4))) float;

__device__ __forceinline__ float lrelu(float x){ return x > 0.f ? x : NEG * x; }

// ================= CSR build: two-level LDS-binned counting sort =================
__global__ void k_hist(const int* __restrict__ src, const int* __restrict__ dst,
                       int E, int N, int NB, int chunk, int* __restrict__ cnt1,
                       int* __restrict__ done){
  __shared__ int hist[256];
  int b = blockIdx.x;
  if (b == 0 && threadIdx.x == 0) *done = 0;
  for (int t = threadIdx.x; t < NB; t += blockDim.x) hist[t] = 0;
  __syncthreads();
  int Et = E + N;
  int s0 = b * chunk, s1 = min(s0 + chunk, Et);
  for (int i = s0 + (int)threadIdx.x; i < s1; i += (int)blockDim.x){
    int d = (i < E) ? dst[i] : (i - E);
    atomicAdd(&hist[d >> 8], 1);
  }
  __syncthreads();
  for (int t = threadIdx.x; t < NB; t += blockDim.x) cnt1[t * NBLK1 + b] = hist[t];
}

// per-bucket scan; last block also scans bucket totals, finalizes off[N], zeroes pool/cnt
__global__ void k_colscan(int* __restrict__ cnt1, int* __restrict__ btot,
                          int* __restrict__ done, int NB, int Et,
                          int* __restrict__ bbase, int* __restrict__ off, int N,
                          float* __restrict__ pool, int* __restrict__ cnt){
  __shared__ int lds[256];
  __shared__ int isLast;
  int b = blockIdx.x;
  int t = threadIdx.x;
  int v0 = cnt1[b * NBLK1 + 2 * t], v1 = cnt1[b * NBLK1 + 2 * t + 1];
  int p = v0 + v1;
  lds[t] = p; __syncthreads();
  #pragma unroll
  for (int s = 1; s < 256; s <<= 1){
    int u = (t >= s) ? lds[t - s] : 0;
    __syncthreads(); lds[t] += u; __syncthreads();
  }
  int epre = lds[t] - p;
  cnt1[b * NBLK1 + 2 * t] = epre;
  cnt1[b * NBLK1 + 2 * t + 1] = epre + v0;
  if (t == 255) btot[b] = lds[255];

  __threadfence();
  if (t == 0) isLast = (atomicAdd(done, 1) == (int)gridDim.x - 1);
  __syncthreads();
  if (!isLast) return;
  __threadfence();

  int v = (t < NB) ? btot[t] : 0;
  lds[t] = v; __syncthreads();
  #pragma unroll
  for (int s = 1; s < 256; s <<= 1){
    int u = (t >= s) ? lds[t - s] : 0;
    __syncthreads(); lds[t] += u; __syncthreads();
  }
  if (t < NB) bbase[t] = lds[t] - v;
  if (t == 0){ bbase[NB] = Et; off[N] = Et; }
  for (int i = t; i < NG * F2; i += 256) pool[i] = 0.f;
  if (t < NG) cnt[t] = 0;
}

__global__ void k_scatter1(const int* __restrict__ src, const int* __restrict__ dst,
                           int E, int N, int NB, int chunk,
                           const int* __restrict__ cnt1, const int* __restrict__ bbase,
                           int* __restrict__ tmp){
  __shared__ int cur[256];
  int b = blockIdx.x;
  for (int t = threadIdx.x; t < NB; t += blockDim.x) cur[t] = bbase[t] + cnt1[t * NBLK1 + b];
  __syncthreads();
  int Et = E + N;
  int s0 = b * chunk, s1 = min(s0 + chunk, Et);
  for (int i = s0 + (int)threadIdx.x; i < s1; i += (int)blockDim.x){
    int s, d;
    if (i < E){ s = src[i]; d = dst[i]; } else { s = d = i - E; }
    int bk = d >> 8;
    int p = atomicAdd(&cur[bk], 1);
    tmp[p] = (s << 8) | (d & 255);
  }
}

__global__ void k_sort2(const int* __restrict__ tmp, const int* __restrict__ bbase,
                        int N, int* __restrict__ off, int* __restrict__ csr_src){
  __shared__ int hist[256];
  __shared__ int pre[256];
  int b = blockIdx.x;
  int t = threadIdx.x;
  hist[t] = 0;
  __syncthreads();
  int g0 = bbase[b], g1 = bbase[b + 1];
  for (int i = g0 + t; i < g1; i += 256) atomicAdd(&hist[tmp[i] & 255], 1);
  __syncthreads();
  int v = hist[t];
  pre[t] = v; __syncthreads();
  #pragma unroll
  for (int s = 1; s < 256; s <<= 1){
    int u = (t >= s) ? pre[t - s] : 0;
    __syncthreads(); pre[t] += u; __syncthreads();
  }
  int ex = pre[t] - v;
  int node = (b << 8) + t;
  if (node < N) off[node] = g0 + ex;
  hist[t] = ex;
  __syncthreads();
  for (int i = g0 + t; i < g1; i += 256){
    int e = tmp[i];
    int p = g0 + atomicAdd(&hist[e & 255], 1);
    csr_src[p] = e >> 8;
  }
}

// ============ MFMA GEMM: slice-major f16 out = A @ W; plus as/ad dots ============
// Output layout: 8 slices of CPS=FO/8 cols: Ch[((slice*M)+row)*CPS + (col%CPS)].
// A: AF32 -> row-major fp32 [M][FI]; else slice-major f16 (CPS_IN=8, FI=64).
template<int FI, int FO, bool AF32>
__global__ void k_gemm_mfma(const void* __restrict__ Av, const float* __restrict__ W,
                            const float* __restrict__ avs, const float* __restrict__ avd,
                            __half* __restrict__ Ch, float* __restrict__ as_, float* __restrict__ ad_,
                            int M){
  constexpr int NT = FO / 16;
  constexpr int KT = FI / 32;
  constexpr int MT = 2;
  constexpr int CPS = FO / 8;
  __shared__ _Float16 blds[NT * KT * 64 * 8];

  int tid = threadIdx.x;
  for (int fl = tid; fl < NT * KT * 64; fl += 256){
    int l = fl & 63, kt = (fl >> 6) % KT, nt = fl / (64 * KT);
    int n = nt * 16 + (l & 15), kb = kt * 32 + (l >> 4) * 8;
    f16x8 v;
    #pragma unroll
    for (int i = 0; i < 8; ++i) v[i] = (_Float16)W[(size_t)(kb + i) * FO + n];
    *(f16x8*)&blds[(size_t)fl * 8] = v;
  }
  __syncthreads();

  int lane = tid & 63, wave = tid >> 6;
  int rbase = lane & 15, kgrp = lane >> 4;
  int r0 = blockIdx.x * (MT * 16 * 4) + wave * (MT * 16);

  f32x4 c[MT][NT];
  #pragma unroll
  for (int mt = 0; mt < MT; ++mt)
    #pragma unroll
    for (int nt = 0; nt < NT; ++nt)
      c[mt][nt] = (f32x4){0.f, 0.f, 0.f, 0.f};

  for (int kt = 0; kt < KT; ++kt){
    f16x8 a[MT];
    #pragma unroll
    for (int mt = 0; mt < MT; ++mt){
      int arow = min(r0 + mt * 16 + rbase, M - 1);
      int kb = kt * 32 + kgrp * 8;
      if (AF32){
        const float* ap = (const float*)Av + (size_t)arow * FI + kb;
        float4 p0 = *(const float4*)ap;
        float4 p1 = *(const float4*)(ap + 4);
        a[mt][0] = (_Float16)p0.x; a[mt][1] = (_Float16)p0.y;
        a[mt][2] = (_Float16)p0.z; a[mt][3] = (_Float16)p0.w;
        a[mt][4] = (_Float16)p1.x; a[mt][5] = (_Float16)p1.y;
        a[mt][6] = (_Float16)p1.z; a[mt][7] = (_Float16)p1.w;
      } else {
        // slice-major input, CPS_IN = 8, kb is a multiple of 8
        const __half* ap = (const __half*)Av + ((size_t)(kb >> 3) * M + arow) * 8;
        a[mt] = *(const f16x8*)ap;
      }
    }
    #pragma unroll
    for (int nt = 0; nt < NT; ++nt){
      f16x8 b = *(f16x8*)&blds[(size_t)((nt * KT + kt) * 64 + lane) * 8];
      #pragma unroll
      for (int mt = 0; mt < MT; ++mt)
        c[mt][nt] = __builtin_amdgcn_mfma_f32_16x16x32_f16(a[mt], b, c[mt][nt], 0, 0, 0);
    }
  }

  float avs_v[NT], avd_v[NT];
  #pragma unroll
  for (int nt = 0; nt < NT; ++nt){
    avs_v[nt] = avs[nt * 16 + rbase];
    avd_v[nt] = avd[nt * 16 + rbase];
  }
  #pragma unroll
  for (int mt = 0; mt < MT; ++mt){
    #pragma unroll
    for (int i = 0; i < 4; ++i){
      int grow = r0 + mt * 16 + kgrp * 4 + i;
      bool ok = grow < M;
      float s1 = 0.f, s2 = 0.f;
      #pragma unroll
      for (int nt = 0; nt < NT; ++nt){
        float d = c[mt][nt][i];
        if (ok){
          int col = nt * 16 + rbase;
          Ch[((size_t)(col / CPS) * M + grow) * CPS + (col % CPS)] = __float2half(d);
        }
        s1 += d * avs_v[nt];
        s2 += d * avd_v[nt];
      }
      #pragma unroll
      for (int msk = 1; msk <= 8; msk <<= 1){
        s1 += __shfl_xor(s1, msk);
        s2 += __shfl_xor(s2, msk);
      }
      if (ok && rbase == 0){ as_[grow] = s1; ad_[grow] = s2; }
    }
  }
}

// -------- sliced aggregation: slice = blockIdx&7 -> lands on one XCD (round-robin) --------
// hs: slice-major [8][N][CPS]; per-XCD working set = N*CPS*2B (L2-resident).
// Wave handles one node for one slice. LPR = CPS/8 lanes per edge; EPW = 64/LPR.
template<int F, int U>
__global__ void k_node_s(const int* __restrict__ off, const int* __restrict__ csr_src,
                         const float* __restrict__ as_, const float* __restrict__ ad_,
                         const __half* __restrict__ hs, const float* __restrict__ bias,
                         __half* __restrict__ outs, int N){
  constexpr int CPS = F / 8;
  constexpr int LPR = CPS / 8;     // 1 (F=64) or 2 (F=128)
  constexpr int EPW = 64 / LPR;
  int lane = threadIdx.x & (WAVE - 1);
  int bid = blockIdx.x;
  int slice = bid & 7;
  int wid = (bid >> 3) * 4 + (int)(threadIdx.x >> 6);
  int node = __builtin_amdgcn_readfirstlane(wid);
  if (node >= N) return;
  int o0 = off[node], o1 = off[node + 1];
  float add = ad_[node];
  int q = lane / LPR;
  int cbase = (lane % LPR) * 8;
  const __half* hb = hs + (size_t)slice * N * CPS + cbase;

  float acc[8];
  #pragma unroll
  for (int i = 0; i < 8; ++i) acc[i] = 0.f;
  float wsum = 0.f;

  for (int jj = o0; jj < o1; jj += U * EPW){
    int s[U]; bool okv[U];
    #pragma unroll
    for (int u = 0; u < U; ++u){
      int j = jj + u * EPW + q;
      okv[u] = j < o1;
      s[u] = csr_src[okv[u] ? j : o0];
    }
    float araw[U];
    #pragma unroll
    for (int u = 0; u < U; ++u) araw[u] = as_[s[u]];
    f16x8 hv[U];
    #pragma unroll
    for (int u = 0; u < U; ++u) hv[u] = *(const f16x8*)(hb + (size_t)s[u] * CPS);
    #pragma unroll
    for (int u = 0; u < U; ++u){
      float w = okv[u] ? __expf(lrelu(araw[u] + add)) : 0.f;
      wsum += w;
      #pragma unroll
      for (int i = 0; i < 8; ++i) acc[i] += w * (float)hv[u][i];
    }
  }

  #pragma unroll
  for (int m = LPR; m < 64; m <<= 1){
    #pragma unroll
    for (int i = 0; i < 8; ++i) acc[i] += __shfl_xor(acc[i], m);
    wsum += __shfl_xor(wsum, m);
  }

  if (q == 0){
    float inv = 1.f / (wsum + 1e-16f);
    f16x8 o;
    #pragma unroll
    for (int i = 0; i < 8; ++i){
      float v = fmaxf(acc[i] * inv + bias[slice * CPS + cbase + i], 0.f);
      o[i] = (_Float16)v;
    }
    *(f16x8*)(outs + ((size_t)slice * N + node) * CPS + cbase) = o;
  }
}

// ---------------- pooling (batch sorted, slice-major input) ----------------
__global__ void k_pool(const __half* __restrict__ hs, const int* __restrict__ batch,
                       float* __restrict__ pool, int* __restrict__ cnt, int N, int strip){
  int f = threadIdx.x;  // 0..127
  int n0 = blockIdx.x * strip;
  if (n0 >= N) return;
  int n1 = min(n0 + strip, N);
  const __half* hb = hs + (size_t)(f >> 4) * N * 16 + (f & 15);
  int g = batch[n0];
  float acc = 0.f;
  int c = 0;
  for (int n = n0; n < n1; ++n){
    int gn = batch[n];
    if (gn != g){
      atomicAdd(&pool[g * F2 + f], acc);
      if (f == 0) atomicAdd(&cnt[g], c);
      acc = 0.f; c = 0; g = gn;
    }
    acc += __half2float(hb[(size_t)n * 16]);
    c++;
  }
  atomicAdd(&pool[g * F2 + f], acc);
  if (f == 0) atomicAdd(&cnt[g], c);
}

// ---------------- final FC ----------------
__global__ void k_fc(const float* __restrict__ pool, const int* __restrict__ cnt,
                     const float* __restrict__ Wfc, const float* __restrict__ bfc,
                     float* __restrict__ out){
  int g = blockIdx.x, o = threadIdx.x;  // 64 x 64
  __shared__ float p[F2];
  float invc = 1.f / fmaxf((float)cnt[g], 1.f);
  for (int k = threadIdx.x; k < F2; k += 64) p[k] = pool[g * F2 + k] * invc;
  __syncthreads();
  float acc = bfc[o];
  for (int k = 0; k < F2; ++k) acc += p[k] * Wfc[k * 64 + o];
  out[g * 64 + o] = acc;
}

extern "C" void kernel_launch(void* const* d_in, const int* in_sizes, int n_in,
                              void* d_out, int out_size, void* d_ws, size_t ws_size,
                              hipStream_t stream){
  const float* x    = (const float*)d_in[0];
  const int*   edge = (const int*)d_in[1];
  const int*   batch= (const int*)d_in[2];
  const float* W1   = (const float*)d_in[3];
  const float* av_s1= (const float*)d_in[4];
  const float* av_d1= (const float*)d_in[5];
  const float* b1   = (const float*)d_in[6];
  const float* W2   = (const float*)d_in[7];
  const float* av_s2= (const float*)d_in[8];
  const float* av_d2= (const float*)d_in[9];
  const float* b2   = (const float*)d_in[10];
  const float* Wfc  = (const float*)d_in[11];
  const float* bfc  = (const float*)d_in[12];
  float* out = (float*)d_out;

  const int N  = in_sizes[2];
  const int E  = in_sizes[1] / 2;
  const int Et = E + N;
  const int NB = (N + 255) >> 8;
  const int* src = edge;
  const int* dst = edge + E;

  char* p = (char*)d_ws;
  auto alloc = [&](size_t bytes)->void*{
    void* r = (void*)p;
    p += (bytes + 255) & ~(size_t)255;
    return r;
  };
  __half* h1  = (__half*)alloc((size_t)N * F1 * 2);   // slice-major [8][N][8]
  __half* h1r = (__half*)alloc((size_t)N * F1 * 2);   // slice-major [8][N][8]
  __half* h2  = (__half*)alloc((size_t)N * F2 * 2);   // slice-major [8][N][16]
  __half* h2r = (__half*)alloc((size_t)N * F2 * 2);   // slice-major [8][N][16]
  float* as1  = (float*)alloc((size_t)N * 4);
  float* ad1  = (float*)alloc((size_t)N * 4);
  float* as2  = (float*)alloc((size_t)N * 4);
  float* ad2  = (float*)alloc((size_t)N * 4);
  float* pool = (float*)alloc((size_t)NG * F2 * 4);
  int* off    = (int*)alloc((size_t)(N + 1) * 4);
  int* csr_src= (int*)alloc((size_t)Et * 4);
  int* tmp    = (int*)alloc((size_t)Et * 4);
  int* cnt1   = (int*)alloc((size_t)256 * NBLK1 * 4);
  int* btot   = (int*)alloc((size_t)256 * 4);
  int* bbase  = (int*)alloc((size_t)257 * 4);
  int* cnt    = (int*)alloc((size_t)NG * 4);
  int* done   = (int*)alloc((size_t)256 * 4);

  // CSR build
  int chunk = (Et + NBLK1 - 1) / NBLK1;
  k_hist<<<NBLK1, 256, 0, stream>>>(src, dst, E, N, NB, chunk, cnt1, done);
  k_colscan<<<NB, 256, 0, stream>>>(cnt1, btot, done, NB, Et, bbase, off, N, pool, cnt);
  k_scatter1<<<NBLK1, 256, 0, stream>>>(src, dst, E, N, NB, chunk, cnt1, bbase, tmp);
  k_sort2<<<NB, 256, 0, stream>>>(tmp, bbase, N, off, csr_src);

  int gemm_blocks = (N + 127) / 128;
  int node_blocks = ((N + 3) / 4) * 8;   // (node-group) x 8 slices

  // layer 1
  k_gemm_mfma<D_IN, F1, true><<<gemm_blocks, 256, 0, stream>>>(x, W1, av_s1, av_d1,
                                                               h1, as1, ad1, N);
  k_node_s<F1, 1><<<node_blocks, 256, 0, stream>>>(off, csr_src, as1, ad1, h1, b1, h1r, N);

  // layer 2
  k_gemm_mfma<F1, F2, false><<<gemm_blocks, 256, 0, stream>>>(h1r, W2, av_s2, av_d2,
                                                              h2, as2, ad2, N);
  k_node_s<F2, 2><<<node_blocks, 256, 0, stream>>>(off, csr_src, as2, ad2, h2, b2, h2r, N);

  // pooling + FC
  int strip = 128;
  int pool_blocks = (N + strip - 1) / strip;
  k_pool<<<pool_blocks, F2, 0, stream>>>(h2r, batch, pool, cnt, N, strip);
  k_fc<<<NG, 64, 0, stream>>>(pool, cnt, Wfc, bfc, out);
}

// Round 13
// 308.507 us; speedup vs baseline: 1.6831x; 1.6831x over previous
//
#include <hip/hip_runtime.h>
#include <hip/hip_fp16.h>

#define WAVE 64

constexpr int D_IN = 128;
constexpr int F1 = 64;
constexpr int F2 = 128;
constexpr int NG = 64;
constexpr float NEG = 0.2f;
constexpr int NBLK1 = 512;       // level-1 binning blocks

using f16x8 = __attribute__((ext_vector_type(8))) _Float16;
using f32x4 = __attribute__((ext_vector_type(4))) float;

__device__ __forceinline__ float lrelu(float x){ return x > 0.f ? x : NEG * x; }

// ================= CSR build: two-level LDS-binned counting sort =================
__global__ void k_hist(const int* __restrict__ src, const int* __restrict__ dst,
                       int E, int N, int NB, int chunk, int* __restrict__ cnt1,
                       int* __restrict__ done){
  __shared__ int hist[256];
  int b = blockIdx.x;
  if (b == 0 && threadIdx.x < 2) done[threadIdx.x] = 0;   // reset last-block flags
  for (int t = threadIdx.x; t < NB; t += blockDim.x) hist[t] = 0;
  __syncthreads();
  int Et = E + N;
  int s0 = b * chunk, s1 = min(s0 + chunk, Et);
  for (int i = s0 + (int)threadIdx.x; i < s1; i += (int)blockDim.x){
    int d = (i < E) ? dst[i] : (i - E);
    atomicAdd(&hist[d >> 8], 1);
  }
  __syncthreads();
  for (int t = threadIdx.x; t < NB; t += blockDim.x) cnt1[t * NBLK1 + b] = hist[t];
}

// per-bucket scan; last block also scans bucket totals, finalizes off[N], zeroes pool/cnt
__global__ void k_colscan(int* __restrict__ cnt1, int* __restrict__ btot,
                          int* __restrict__ done, int NB, int Et,
                          int* __restrict__ bbase, int* __restrict__ off, int N,
                          float* __restrict__ pool, int* __restrict__ cnt){
  __shared__ int lds[256];
  __shared__ int isLast;
  int b = blockIdx.x;
  int t = threadIdx.x;
  int v0 = cnt1[b * NBLK1 + 2 * t], v1 = cnt1[b * NBLK1 + 2 * t + 1];
  int p = v0 + v1;
  lds[t] = p; __syncthreads();
  #pragma unroll
  for (int s = 1; s < 256; s <<= 1){
    int u = (t >= s) ? lds[t - s] : 0;
    __syncthreads(); lds[t] += u; __syncthreads();
  }
  int epre = lds[t] - p;
  cnt1[b * NBLK1 + 2 * t] = epre;
  cnt1[b * NBLK1 + 2 * t + 1] = epre + v0;
  if (t == 255) btot[b] = lds[255];

  __threadfence();
  if (t == 0) isLast = (atomicAdd(done, 1) == (int)gridDim.x - 1);
  __syncthreads();
  if (!isLast) return;
  __threadfence();

  int v = (t < NB) ? btot[t] : 0;
  lds[t] = v; __syncthreads();
  #pragma unroll
  for (int s = 1; s < 256; s <<= 1){
    int u = (t >= s) ? lds[t - s] : 0;
    __syncthreads(); lds[t] += u; __syncthreads();
  }
  if (t < NB) bbase[t] = lds[t] - v;
  if (t == 0){ bbase[NB] = Et; off[N] = Et; }
  for (int i = t; i < NG * F2; i += 256) pool[i] = 0.f;
  if (t < NG) cnt[t] = 0;
}

__global__ void k_scatter1(const int* __restrict__ src, const int* __restrict__ dst,
                           int E, int N, int NB, int chunk,
                           const int* __restrict__ cnt1, const int* __restrict__ bbase,
                           int* __restrict__ tmp){
  __shared__ int cur[256];
  int b = blockIdx.x;
  for (int t = threadIdx.x; t < NB; t += blockDim.x) cur[t] = bbase[t] + cnt1[t * NBLK1 + b];
  __syncthreads();
  int Et = E + N;
  int s0 = b * chunk, s1 = min(s0 + chunk, Et);
  for (int i = s0 + (int)threadIdx.x; i < s1; i += (int)blockDim.x){
    int s, d;
    if (i < E){ s = src[i]; d = dst[i]; } else { s = d = i - E; }
    int bk = d >> 8;
    int p = atomicAdd(&cur[bk], 1);
    tmp[p] = (s << 8) | (d & 255);
  }
}

__global__ void k_sort2(const int* __restrict__ tmp, const int* __restrict__ bbase,
                        int N, int* __restrict__ off, int* __restrict__ csr_src){
  __shared__ int hist[256];
  __shared__ int pre[256];
  int b = blockIdx.x;
  int t = threadIdx.x;
  hist[t] = 0;
  __syncthreads();
  int g0 = bbase[b], g1 = bbase[b + 1];
  for (int i = g0 + t; i < g1; i += 256) atomicAdd(&hist[tmp[i] & 255], 1);
  __syncthreads();
  int v = hist[t];
  pre[t] = v; __syncthreads();
  #pragma unroll
  for (int s = 1; s < 256; s <<= 1){
    int u = (t >= s) ? pre[t - s] : 0;
    __syncthreads(); pre[t] += u; __syncthreads();
  }
  int ex = pre[t] - v;
  int node = (b << 8) + t;
  if (node < N) off[node] = g0 + ex;
  hist[t] = ex;
  __syncthreads();
  for (int i = g0 + t; i < g1; i += 256){
    int e = tmp[i];
    int p = g0 + atomicAdd(&hist[e & 255], 1);
    csr_src[p] = e >> 8;
  }
}

// ============ MFMA GEMM: Ch[M,FO](fp16) = A[M,FI] @ W[FI,FO]; plus as/ad dots ============
template<int FI, int FO, bool AF32>
__global__ void k_gemm_mfma(const void* __restrict__ Av, const float* __restrict__ W,
                            const float* __restrict__ avs, const float* __restrict__ avd,
                            __half* __restrict__ Ch, float* __restrict__ as_, float* __restrict__ ad_,
                            int M){
  constexpr int NT = FO / 16;
  constexpr int KT = FI / 32;
  constexpr int MT = 2;
  __shared__ _Float16 blds[NT * KT * 64 * 8];

  int tid = threadIdx.x;
  for (int fl = tid; fl < NT * KT * 64; fl += 256){
    int l = fl & 63, kt = (fl >> 6) % KT, nt = fl / (64 * KT);
    int n = nt * 16 + (l & 15), kb = kt * 32 + (l >> 4) * 8;
    f16x8 v;
    #pragma unroll
    for (int i = 0; i < 8; ++i) v[i] = (_Float16)W[(size_t)(kb + i) * FO + n];
    *(f16x8*)&blds[(size_t)fl * 8] = v;
  }
  __syncthreads();

  int lane = tid & 63, wave = tid >> 6;
  int rbase = lane & 15, kgrp = lane >> 4;
  int r0 = blockIdx.x * (MT * 16 * 4) + wave * (MT * 16);

  f32x4 c[MT][NT];
  #pragma unroll
  for (int mt = 0; mt < MT; ++mt)
    #pragma unroll
    for (int nt = 0; nt < NT; ++nt)
      c[mt][nt] = (f32x4){0.f, 0.f, 0.f, 0.f};

  for (int kt = 0; kt < KT; ++kt){
    f16x8 a[MT];
    #pragma unroll
    for (int mt = 0; mt < MT; ++mt){
      int arow = min(r0 + mt * 16 + rbase, M - 1);
      if (AF32){
        const float* ap = (const float*)Av + (size_t)arow * FI + kt * 32 + kgrp * 8;
        float4 p0 = *(const float4*)ap;
        float4 p1 = *(const float4*)(ap + 4);
        a[mt][0] = (_Float16)p0.x; a[mt][1] = (_Float16)p0.y;
        a[mt][2] = (_Float16)p0.z; a[mt][3] = (_Float16)p0.w;
        a[mt][4] = (_Float16)p1.x; a[mt][5] = (_Float16)p1.y;
        a[mt][6] = (_Float16)p1.z; a[mt][7] = (_Float16)p1.w;
      } else {
        const __half* ap = (const __half*)Av + (size_t)arow * FI + kt * 32 + kgrp * 8;
        a[mt] = *(const f16x8*)ap;
      }
    }
    #pragma unroll
    for (int nt = 0; nt < NT; ++nt){
      f16x8 b = *(f16x8*)&blds[(size_t)((nt * KT + kt) * 64 + lane) * 8];
      #pragma unroll
      for (int mt = 0; mt < MT; ++mt)
        c[mt][nt] = __builtin_amdgcn_mfma_f32_16x16x32_f16(a[mt], b, c[mt][nt], 0, 0, 0);
    }
  }

  float avs_v[NT], avd_v[NT];
  #pragma unroll
  for (int nt = 0; nt < NT; ++nt){
    avs_v[nt] = avs[nt * 16 + rbase];
    avd_v[nt] = avd[nt * 16 + rbase];
  }
  #pragma unroll
  for (int mt = 0; mt < MT; ++mt){
    #pragma unroll
    for (int i = 0; i < 4; ++i){
      int grow = r0 + mt * 16 + kgrp * 4 + i;
      bool ok = grow < M;
      float s1 = 0.f, s2 = 0.f;
      #pragma unroll
      for (int nt = 0; nt < NT; ++nt){
        float d = c[mt][nt][i];
        if (ok) Ch[(size_t)grow * FO + nt * 16 + rbase] = __float2half(d);
        s1 += d * avs_v[nt];
        s2 += d * avd_v[nt];
      }
      #pragma unroll
      for (int msk = 1; msk <= 8; msk <<= 1){
        s1 += __shfl_xor(s1, msk);
        s2 += __shfl_xor(s2, msk);
      }
      if (ok && rbase == 0){ as_[grow] = s1; ad_[grow] = s2; }
    }
  }
}

// -------- aggregation: grouped gather + fused weight, 4-deep software pipeline --------
template<int F>
__global__ void k_node(const int* __restrict__ off, const int* __restrict__ csr_src,
                       const float* __restrict__ as_, const float* __restrict__ ad_,
                       const __half* __restrict__ h, const float* __restrict__ bias,
                       __half* __restrict__ outh, int N){
  constexpr int LPR = F / 8;
  constexpr int EPW = 64 / LPR;
  constexpr int U = 4;
  int lane = threadIdx.x & (WAVE - 1);
  int wid = (int)((blockIdx.x * blockDim.x + threadIdx.x) >> 6);
  int node = __builtin_amdgcn_readfirstlane(wid);
  if (node >= N) return;
  int o0 = off[node], o1 = off[node + 1];
  float add = ad_[node];
  int q = lane / LPR;
  int cbase = (lane % LPR) * 8;

  float acc[8];
  #pragma unroll
  for (int i = 0; i < 8; ++i) acc[i] = 0.f;
  float wsum = 0.f;

  for (int jj = o0; jj < o1; jj += U * EPW){
    int s[U]; bool okv[U];
    #pragma unroll
    for (int u = 0; u < U; ++u){
      int j = jj + u * EPW + q;
      okv[u] = j < o1;
      s[u] = csr_src[okv[u] ? j : o0];
    }
    float araw[U];
    #pragma unroll
    for (int u = 0; u < U; ++u) araw[u] = as_[s[u]];
    f16x8 hv[U];
    #pragma unroll
    for (int u = 0; u < U; ++u) hv[u] = *(const f16x8*)(h + (size_t)s[u] * F + cbase);
    #pragma unroll
    for (int u = 0; u < U; ++u){
      float w = okv[u] ? __expf(lrelu(araw[u] + add)) : 0.f;
      wsum += w;
      #pragma unroll
      for (int i = 0; i < 8; ++i) acc[i] += w * (float)hv[u][i];
    }
  }

  #pragma unroll
  for (int m = LPR; m < 64; m <<= 1){
    #pragma unroll
    for (int i = 0; i < 8; ++i) acc[i] += __shfl_xor(acc[i], m);
    wsum += __shfl_xor(wsum, m);
  }

  if (q == 0){
    float inv = 1.f / (wsum + 1e-16f);
    f16x8 o;
    #pragma unroll
    for (int i = 0; i < 8; ++i){
      float v = fmaxf(acc[i] * inv + bias[cbase + i], 0.f);
      o[i] = (_Float16)v;
    }
    *(f16x8*)(outh + (size_t)node * F + cbase) = o;
  }
}

// ------- pooling (batch sorted) + fused FC via last-block pattern -------
__global__ void k_pool_fc(const __half* __restrict__ h, const int* __restrict__ batch,
                          float* __restrict__ pool, int* __restrict__ cnt, int N, int strip,
                          int* __restrict__ done,
                          const float* __restrict__ Wfc, const float* __restrict__ bfc,
                          float* __restrict__ out){
  __shared__ int isLast;
  int f = threadIdx.x;  // 0..127
  int n0 = blockIdx.x * strip;
  int n1 = min(n0 + strip, N);
  if (n0 < N){
    int g = batch[n0];
    float acc = 0.f;
    int c = 0;
    for (int n = n0; n < n1; ++n){
      int gn = batch[n];
      if (gn != g){
        atomicAdd(&pool[g * F2 + f], acc);
        if (f == 0) atomicAdd(&cnt[g], c);
        acc = 0.f; c = 0; g = gn;
      }
      acc += __half2float(h[(size_t)n * F2 + f]);
      c++;
    }
    atomicAdd(&pool[g * F2 + f], acc);
    if (f == 0) atomicAdd(&cnt[g], c);
  }

  __threadfence();
  if (f == 0) isLast = (atomicAdd(done, 1) == (int)gridDim.x - 1);
  __syncthreads();
  if (!isLast) return;
  __threadfence();

  // final FC: out[g][o] = (pool[g]/cnt[g]) . Wfc[:,o] + bfc[o]
  for (int idx = f; idx < NG * 64; idx += 128){
    int g = idx >> 6, o = idx & 63;
    float invc = 1.f / fmaxf((float)cnt[g], 1.f);
    float acc = bfc[o];
    const float* pg = pool + g * F2;
    for (int k = 0; k < F2; ++k) acc += pg[k] * invc * Wfc[k * 64 + o];
    out[idx] = acc;
  }
}

extern "C" void kernel_launch(void* const* d_in, const int* in_sizes, int n_in,
                              void* d_out, int out_size, void* d_ws, size_t ws_size,
                              hipStream_t stream){
  const float* x    = (const float*)d_in[0];
  const int*   edge = (const int*)d_in[1];
  const int*   batch= (const int*)d_in[2];
  const float* W1   = (const float*)d_in[3];
  const float* av_s1= (const float*)d_in[4];
  const float* av_d1= (const float*)d_in[5];
  const float* b1   = (const float*)d_in[6];
  const float* W2   = (const float*)d_in[7];
  const float* av_s2= (const float*)d_in[8];
  const float* av_d2= (const float*)d_in[9];
  const float* b2   = (const float*)d_in[10];
  const float* Wfc  = (const float*)d_in[11];
  const float* bfc  = (const float*)d_in[12];
  float* out = (float*)d_out;

  const int N  = in_sizes[2];
  const int E  = in_sizes[1] / 2;
  const int Et = E + N;
  const int NB = (N + 255) >> 8;
  const int* src = edge;
  const int* dst = edge + E;

  char* p = (char*)d_ws;
  auto alloc = [&](size_t bytes)->void*{
    void* r = (void*)p;
    p += (bytes + 255) & ~(size_t)255;
    return r;
  };
  __half* h1  = (__half*)alloc((size_t)N * F1 * 2);
  __half* h1r = (__half*)alloc((size_t)N * F1 * 2);
  __half* h2  = (__half*)alloc((size_t)N * F2 * 2);
  __half* h2r = (__half*)alloc((size_t)N * F2 * 2);
  float* as1  = (float*)alloc((size_t)N * 4);
  float* ad1  = (float*)alloc((size_t)N * 4);
  float* as2  = (float*)alloc((size_t)N * 4);
  float* ad2  = (float*)alloc((size_t)N * 4);
  float* pool = (float*)alloc((size_t)NG * F2 * 4);
  int* off    = (int*)alloc((size_t)(N + 1) * 4);
  int* csr_src= (int*)alloc((size_t)Et * 4);
  int* tmp    = (int*)alloc((size_t)Et * 4);
  int* cnt1   = (int*)alloc((size_t)256 * NBLK1 * 4);
  int* btot   = (int*)alloc((size_t)256 * 4);
  int* bbase  = (int*)alloc((size_t)257 * 4);
  int* cnt    = (int*)alloc((size_t)NG * 4);
  int* done   = (int*)alloc((size_t)256 * 4);

  // CSR build; colscan's last block also scans buckets and zeroes pool/cnt
  int chunk = (Et + NBLK1 - 1) / NBLK1;
  k_hist<<<NBLK1, 256, 0, stream>>>(src, dst, E, N, NB, chunk, cnt1, done);
  k_colscan<<<NB, 256, 0, stream>>>(cnt1, btot, done, NB, Et, bbase, off, N, pool, cnt);
  k_scatter1<<<NBLK1, 256, 0, stream>>>(src, dst, E, N, NB, chunk, cnt1, bbase, tmp);
  k_sort2<<<NB, 256, 0, stream>>>(tmp, bbase, N, off, csr_src);

  int gemm_blocks = (N + 127) / 128;
  int node_blocks = (N + 3) / 4;   // 4 waves (nodes) per 256-thread block

  // layer 1
  k_gemm_mfma<D_IN, F1, true><<<gemm_blocks, 256, 0, stream>>>(x, W1, av_s1, av_d1,
                                                               h1, as1, ad1, N);
  k_node<F1><<<node_blocks, 256, 0, stream>>>(off, csr_src, as1, ad1, h1, b1, h1r, N);

  // layer 2
  k_gemm_mfma<F1, F2, false><<<gemm_blocks, 256, 0, stream>>>(h1r, W2, av_s2, av_d2,
                                                              h2, as2, ad2, N);
  k_node<F2><<<node_blocks, 256, 0, stream>>>(off, csr_src, as2, ad2, h2, b2, h2r, N);

  // pooling + FC (fused, last-block)
  int strip = 128;
  int pool_blocks = (N + strip - 1) / strip;
  k_pool_fc<<<pool_blocks, F2, 0, stream>>>(h2r, batch, pool, cnt, N, strip,
                                            done + 1, Wfc, bfc, out);
}

// Round 14
// 203.327 us; speedup vs baseline: 2.5537x; 1.5173x over previous
//
#include <hip/hip_runtime.h>
#include <hip/hip_fp16.h>

#define WAVE 64

constexpr int D_IN = 128;
constexpr int F1 = 64;
constexpr int F2 = 128;
constexpr int NG = 64;
constexpr float NEG = 0.2f;
constexpr int NBLK1 = 512;       // level-1 binning blocks

using f16x8 = __attribute__((ext_vector_type(8))) _Float16;
using f32x4 = __attribute__((ext_vector_type(4))) float;

__device__ __forceinline__ float lrelu(float x){ return x > 0.f ? x : NEG * x; }

// ================= CSR build: two-level LDS-binned counting sort =================
__global__ void k_hist(const int* __restrict__ src, const int* __restrict__ dst,
                       int E, int N, int NB, int chunk, int* __restrict__ cnt1,
                       int* __restrict__ done){
  __shared__ int hist[256];
  int b = blockIdx.x;
  if (b == 0 && threadIdx.x == 0) *done = 0;   // reset last-block flag
  for (int t = threadIdx.x; t < NB; t += blockDim.x) hist[t] = 0;
  __syncthreads();
  int Et = E + N;
  int s0 = b * chunk, s1 = min(s0 + chunk, Et);
  for (int i = s0 + (int)threadIdx.x; i < s1; i += (int)blockDim.x){
    int d = (i < E) ? dst[i] : (i - E);
    atomicAdd(&hist[d >> 8], 1);
  }
  __syncthreads();
  for (int t = threadIdx.x; t < NB; t += blockDim.x) cnt1[t * NBLK1 + b] = hist[t];
}

// per-bucket scan; last block also scans bucket totals, finalizes off[N], zeroes pool/cnt
__global__ void k_colscan(int* __restrict__ cnt1, int* __restrict__ btot,
                          int* __restrict__ done, int NB, int Et,
                          int* __restrict__ bbase, int* __restrict__ off, int N,
                          float* __restrict__ pool, int* __restrict__ cnt){
  __shared__ int lds[256];
  __shared__ int isLast;
  int b = blockIdx.x;
  int t = threadIdx.x;
  int v0 = cnt1[b * NBLK1 + 2 * t], v1 = cnt1[b * NBLK1 + 2 * t + 1];
  int p = v0 + v1;
  lds[t] = p; __syncthreads();
  #pragma unroll
  for (int s = 1; s < 256; s <<= 1){
    int u = (t >= s) ? lds[t - s] : 0;
    __syncthreads(); lds[t] += u; __syncthreads();
  }
  int epre = lds[t] - p;
  cnt1[b * NBLK1 + 2 * t] = epre;
  cnt1[b * NBLK1 + 2 * t + 1] = epre + v0;
  if (t == 255) btot[b] = lds[255];

  __threadfence();
  if (t == 0) isLast = (atomicAdd(done, 1) == (int)gridDim.x - 1);
  __syncthreads();
  if (!isLast) return;
  __threadfence();

  int v = (t < NB) ? btot[t] : 0;
  lds[t] = v; __syncthreads();
  #pragma unroll
  for (int s = 1; s < 256; s <<= 1){
    int u = (t >= s) ? lds[t - s] : 0;
    __syncthreads(); lds[t] += u; __syncthreads();
  }
  if (t < NB) bbase[t] = lds[t] - v;
  if (t == 0){ bbase[NB] = Et; off[N] = Et; }
  for (int i = t; i < NG * F2; i += 256) pool[i] = 0.f;
  if (t < NG) cnt[t] = 0;
}

__global__ void k_scatter1(const int* __restrict__ src, const int* __restrict__ dst,
                           int E, int N, int NB, int chunk,
                           const int* __restrict__ cnt1, const int* __restrict__ bbase,
                           int* __restrict__ tmp){
  __shared__ int cur[256];
  int b = blockIdx.x;
  for (int t = threadIdx.x; t < NB; t += blockDim.x) cur[t] = bbase[t] + cnt1[t * NBLK1 + b];
  __syncthreads();
  int Et = E + N;
  int s0 = b * chunk, s1 = min(s0 + chunk, Et);
  for (int i = s0 + (int)threadIdx.x; i < s1; i += (int)blockDim.x){
    int s, d;
    if (i < E){ s = src[i]; d = dst[i]; } else { s = d = i - E; }
    int bk = d >> 8;
    int p = atomicAdd(&cur[bk], 1);
    tmp[p] = (s << 8) | (d & 255);
  }
}

__global__ void k_sort2(const int* __restrict__ tmp, const int* __restrict__ bbase,
                        int N, int* __restrict__ off, int* __restrict__ csr_src){
  __shared__ int hist[256];
  __shared__ int pre[256];
  int b = blockIdx.x;
  int t = threadIdx.x;
  hist[t] = 0;
  __syncthreads();
  int g0 = bbase[b], g1 = bbase[b + 1];
  for (int i = g0 + t; i < g1; i += 256) atomicAdd(&hist[tmp[i] & 255], 1);
  __syncthreads();
  int v = hist[t];
  pre[t] = v; __syncthreads();
  #pragma unroll
  for (int s = 1; s < 256; s <<= 1){
    int u = (t >= s) ? pre[t - s] : 0;
    __syncthreads(); pre[t] += u; __syncthreads();
  }
  int ex = pre[t] - v;
  int node = (b << 8) + t;
  if (node < N) off[node] = g0 + ex;
  hist[t] = ex;
  __syncthreads();
  for (int i = g0 + t; i < g1; i += 256){
    int e = tmp[i];
    int p = g0 + atomicAdd(&hist[e & 255], 1);
    csr_src[p] = e >> 8;
  }
}

// ============ MFMA GEMM: Ch[M,FO](fp16) = A[M,FI] @ W[FI,FO]; plus as/ad dots ============
template<int FI, int FO, bool AF32>
__global__ void k_gemm_mfma(const void* __restrict__ Av, const float* __restrict__ W,
                            const float* __restrict__ avs, const float* __restrict__ avd,
                            __half* __restrict__ Ch, float* __restrict__ as_, float* __restrict__ ad_,
                            int M){
  constexpr int NT = FO / 16;
  constexpr int KT = FI / 32;
  constexpr int MT = 2;
  __shared__ _Float16 blds[NT * KT * 64 * 8];

  int tid = threadIdx.x;
  for (int fl = tid; fl < NT * KT * 64; fl += 256){
    int l = fl & 63, kt = (fl >> 6) % KT, nt = fl / (64 * KT);
    int n = nt * 16 + (l & 15), kb = kt * 32 + (l >> 4) * 8;
    f16x8 v;
    #pragma unroll
    for (int i = 0; i < 8; ++i) v[i] = (_Float16)W[(size_t)(kb + i) * FO + n];
    *(f16x8*)&blds[(size_t)fl * 8] = v;
  }
  __syncthreads();

  int lane = tid & 63, wave = tid >> 6;
  int rbase = lane & 15, kgrp = lane >> 4;
  int r0 = blockIdx.x * (MT * 16 * 4) + wave * (MT * 16);

  f32x4 c[MT][NT];
  #pragma unroll
  for (int mt = 0; mt < MT; ++mt)
    #pragma unroll
    for (int nt = 0; nt < NT; ++nt)
      c[mt][nt] = (f32x4){0.f, 0.f, 0.f, 0.f};

  for (int kt = 0; kt < KT; ++kt){
    f16x8 a[MT];
    #pragma unroll
    for (int mt = 0; mt < MT; ++mt){
      int arow = min(r0 + mt * 16 + rbase, M - 1);
      if (AF32){
        const float* ap = (const float*)Av + (size_t)arow * FI + kt * 32 + kgrp * 8;
        float4 p0 = *(const float4*)ap;
        float4 p1 = *(const float4*)(ap + 4);
        a[mt][0] = (_Float16)p0.x; a[mt][1] = (_Float16)p0.y;
        a[mt][2] = (_Float16)p0.z; a[mt][3] = (_Float16)p0.w;
        a[mt][4] = (_Float16)p1.x; a[mt][5] = (_Float16)p1.y;
        a[mt][6] = (_Float16)p1.z; a[mt][7] = (_Float16)p1.w;
      } else {
        const __half* ap = (const __half*)Av + (size_t)arow * FI + kt * 32 + kgrp * 8;
        a[mt] = *(const f16x8*)ap;
      }
    }
    #pragma unroll
    for (int nt = 0; nt < NT; ++nt){
      f16x8 b = *(f16x8*)&blds[(size_t)((nt * KT + kt) * 64 + lane) * 8];
      #pragma unroll
      for (int mt = 0; mt < MT; ++mt)
        c[mt][nt] = __builtin_amdgcn_mfma_f32_16x16x32_f16(a[mt], b, c[mt][nt], 0, 0, 0);
    }
  }

  float avs_v[NT], avd_v[NT];
  #pragma unroll
  for (int nt = 0; nt < NT; ++nt){
    avs_v[nt] = avs[nt * 16 + rbase];
    avd_v[nt] = avd[nt * 16 + rbase];
  }
  #pragma unroll
  for (int mt = 0; mt < MT; ++mt){
    #pragma unroll
    for (int i = 0; i < 4; ++i){
      int grow = r0 + mt * 16 + kgrp * 4 + i;
      bool ok = grow < M;
      float s1 = 0.f, s2 = 0.f;
      #pragma unroll
      for (int nt = 0; nt < NT; ++nt){
        float d = c[mt][nt][i];
        if (ok) Ch[(size_t)grow * FO + nt * 16 + rbase] = __float2half(d);
        s1 += d * avs_v[nt];
        s2 += d * avd_v[nt];
      }
      #pragma unroll
      for (int msk = 1; msk <= 8; msk <<= 1){
        s1 += __shfl_xor(s1, msk);
        s2 += __shfl_xor(s2, msk);
      }
      if (ok && rbase == 0){ as_[grow] = s1; ad_[grow] = s2; }
    }
  }
}

// -------- aggregation: grouped gather + fused weight, 4-deep software pipeline --------
template<int F>
__global__ void k_node(const int* __restrict__ off, const int* __restrict__ csr_src,
                       const float* __restrict__ as_, const float* __restrict__ ad_,
                       const __half* __restrict__ h, const float* __restrict__ bias,
                       __half* __restrict__ outh, int N){
  constexpr int LPR = F / 8;
  constexpr int EPW = 64 / LPR;
  constexpr int U = 4;
  int lane = threadIdx.x & (WAVE - 1);
  int wid = (int)((blockIdx.x * blockDim.x + threadIdx.x) >> 6);
  int node = __builtin_amdgcn_readfirstlane(wid);
  if (node >= N) return;
  int o0 = off[node], o1 = off[node + 1];
  float add = ad_[node];
  int q = lane / LPR;
  int cbase = (lane % LPR) * 8;

  float acc[8];
  #pragma unroll
  for (int i = 0; i < 8; ++i) acc[i] = 0.f;
  float wsum = 0.f;

  for (int jj = o0; jj < o1; jj += U * EPW){
    int s[U]; bool okv[U];
    #pragma unroll
    for (int u = 0; u < U; ++u){
      int j = jj + u * EPW + q;
      okv[u] = j < o1;
      s[u] = csr_src[okv[u] ? j : o0];
    }
    float araw[U];
    #pragma unroll
    for (int u = 0; u < U; ++u) araw[u] = as_[s[u]];
    f16x8 hv[U];
    #pragma unroll
    for (int u = 0; u < U; ++u) hv[u] = *(const f16x8*)(h + (size_t)s[u] * F + cbase);
    #pragma unroll
    for (int u = 0; u < U; ++u){
      float w = okv[u] ? __expf(lrelu(araw[u] + add)) : 0.f;
      wsum += w;
      #pragma unroll
      for (int i = 0; i < 8; ++i) acc[i] += w * (float)hv[u][i];
    }
  }

  #pragma unroll
  for (int m = LPR; m < 64; m <<= 1){
    #pragma unroll
    for (int i = 0; i < 8; ++i) acc[i] += __shfl_xor(acc[i], m);
    wsum += __shfl_xor(wsum, m);
  }

  if (q == 0){
    float inv = 1.f / (wsum + 1e-16f);
    f16x8 o;
    #pragma unroll
    for (int i = 0; i < 8; ++i){
      float v = fmaxf(acc[i] * inv + bias[cbase + i], 0.f);
      o[i] = (_Float16)v;
    }
    *(f16x8*)(outh + (size_t)node * F + cbase) = o;
  }
}

// ---------------- pooling (batch sorted): strip reduction, few atomics ----------------
__global__ void k_pool(const __half* __restrict__ h, const int* __restrict__ batch,
                       float* __restrict__ pool, int* __restrict__ cnt, int N, int strip){
  int f = threadIdx.x;  // 0..127
  int n0 = blockIdx.x * strip;
  if (n0 >= N) return;
  int n1 = min(n0 + strip, N);
  int g = batch[n0];
  float acc = 0.f;
  int c = 0;
  for (int n = n0; n < n1; ++n){
    int gn = batch[n];
    if (gn != g){
      atomicAdd(&pool[g * F2 + f], acc);
      if (f == 0) atomicAdd(&cnt[g], c);
      acc = 0.f; c = 0; g = gn;
    }
    acc += __half2float(h[(size_t)n * F2 + f]);
    c++;
  }
  atomicAdd(&pool[g * F2 + f], acc);
  if (f == 0) atomicAdd(&cnt[g], c);
}

// ---------------- final FC ----------------
__global__ void k_fc(const float* __restrict__ pool, const int* __restrict__ cnt,
                     const float* __restrict__ Wfc, const float* __restrict__ bfc,
                     float* __restrict__ out){
  int g = blockIdx.x, o = threadIdx.x;  // 64 x 64
  __shared__ float p[F2];
  float invc = 1.f / fmaxf((float)cnt[g], 1.f);
  for (int k = threadIdx.x; k < F2; k += 64) p[k] = pool[g * F2 + k] * invc;
  __syncthreads();
  float acc = bfc[o];
  for (int k = 0; k < F2; ++k) acc += p[k] * Wfc[k * 64 + o];
  out[g * 64 + o] = acc;
}

extern "C" void kernel_launch(void* const* d_in, const int* in_sizes, int n_in,
                              void* d_out, int out_size, void* d_ws, size_t ws_size,
                              hipStream_t stream){
  const float* x    = (const float*)d_in[0];
  const int*   edge = (const int*)d_in[1];
  const int*   batch= (const int*)d_in[2];
  const float* W1   = (const float*)d_in[3];
  const float* av_s1= (const float*)d_in[4];
  const float* av_d1= (const float*)d_in[5];
  const float* b1   = (const float*)d_in[6];
  const float* W2   = (const float*)d_in[7];
  const float* av_s2= (const float*)d_in[8];
  const float* av_d2= (const float*)d_in[9];
  const float* b2   = (const float*)d_in[10];
  const float* Wfc  = (const float*)d_in[11];
  const float* bfc  = (const float*)d_in[12];
  float* out = (float*)d_out;

  const int N  = in_sizes[2];
  const int E  = in_sizes[1] / 2;
  const int Et = E + N;
  const int NB = (N + 255) >> 8;
  const int* src = edge;
  const int* dst = edge + E;

  char* p = (char*)d_ws;
  auto alloc = [&](size_t bytes)->void*{
    void* r = (void*)p;
    p += (bytes + 255) & ~(size_t)255;
    return r;
  };
  __half* h1  = (__half*)alloc((size_t)N * F1 * 2);
  __half* h1r = (__half*)alloc((size_t)N * F1 * 2);
  __half* h2  = (__half*)alloc((size_t)N * F2 * 2);
  __half* h2r = (__half*)alloc((size_t)N * F2 * 2);
  float* as1  = (float*)alloc((size_t)N * 4);
  float* ad1  = (float*)alloc((size_t)N * 4);
  float* as2  = (float*)alloc((size_t)N * 4);
  float* ad2  = (float*)alloc((size_t)N * 4);
  float* pool = (float*)alloc((size_t)NG * F2 * 4);
  int* off    = (int*)alloc((size_t)(N + 1) * 4);
  int* csr_src= (int*)alloc((size_t)Et * 4);
  int* tmp    = (int*)alloc((size_t)Et * 4);
  int* cnt1   = (int*)alloc((size_t)256 * NBLK1 * 4);
  int* btot   = (int*)alloc((size_t)256 * 4);
  int* bbase  = (int*)alloc((size_t)257 * 4);
  int* cnt    = (int*)alloc((size_t)NG * 4);
  int* done   = (int*)alloc((size_t)256 * 4);

  // CSR build; colscan's last block also scans buckets and zeroes pool/cnt
  int chunk = (Et + NBLK1 - 1) / NBLK1;
  k_hist<<<NBLK1, 256, 0, stream>>>(src, dst, E, N, NB, chunk, cnt1, done);
  k_colscan<<<NB, 256, 0, stream>>>(cnt1, btot, done, NB, Et, bbase, off, N, pool, cnt);
  k_scatter1<<<NBLK1, 256, 0, stream>>>(src, dst, E, N, NB, chunk, cnt1, bbase, tmp);
  k_sort2<<<NB, 256, 0, stream>>>(tmp, bbase, N, off, csr_src);

  int gemm_blocks = (N + 127) / 128;
  int node_blocks = (N + 3) / 4;   // 4 waves (nodes) per 256-thread block

  // layer 1
  k_gemm_mfma<D_IN, F1, true><<<gemm_blocks, 256, 0, stream>>>(x, W1, av_s1, av_d1,
                                                               h1, as1, ad1, N);
  k_node<F1><<<node_blocks, 256, 0, stream>>>(off, csr_src, as1, ad1, h1, b1, h1r, N);

  // layer 2
  k_gemm_mfma<F1, F2, false><<<gemm_blocks, 256, 0, stream>>>(h1r, W2, av_s2, av_d2,
                                                              h2, as2, ad2, N);
  k_node<F2><<<node_blocks, 256, 0, stream>>>(off, csr_src, as2, ad2, h2, b2, h2r, N);

  // pooling + FC
  int strip = 128;
  int pool_blocks = (N + strip - 1) / strip;
  k_pool<<<pool_blocks, F2, 0, stream>>>(h2r, batch, pool, cnt, N, strip);
  k_fc<<<NG, 64, 0, stream>>>(pool, cnt, Wfc, bfc, out);
}

// Round 15
// 201.054 us; speedup vs baseline: 2.5826x; 1.0113x over previous
//
#include <hip/hip_runtime.h>
#include <hip/hip_fp16.h>

#define WAVE 64

constexpr int D_IN = 128;
constexpr int F1 = 64;
constexpr int F2 = 128;
constexpr int NG = 64;
constexpr float NEG = 0.2f;
constexpr int NBLK1 = 512;       // level-1 binning blocks

using f16x8 = __attribute__((ext_vector_type(8))) _Float16;
using f32x4 = __attribute__((ext_vector_type(4))) float;

__device__ __forceinline__ float lrelu(float x){ return x > 0.f ? x : NEG * x; }

// ================= CSR build bodies =================
__device__ __forceinline__ void hist_body(int* hist, int b, const int* __restrict__ src,
                                          const int* __restrict__ dst, int E, int N, int NB,
                                          int chunk, int* __restrict__ cnt1,
                                          int* __restrict__ done){
  if (b == 0 && threadIdx.x == 0) *done = 0;   // reset last-block flag
  for (int t = threadIdx.x; t < NB; t += blockDim.x) hist[t] = 0;
  __syncthreads();
  int Et = E + N;
  int s0 = b * chunk, s1 = min(s0 + chunk, Et);
  for (int i = s0 + (int)threadIdx.x; i < s1; i += (int)blockDim.x){
    int d = (i < E) ? dst[i] : (i - E);
    atomicAdd(&hist[d >> 8], 1);
  }
  __syncthreads();
  for (int t = threadIdx.x; t < NB; t += blockDim.x) cnt1[t * NBLK1 + b] = hist[t];
}

// ============ MFMA GEMM body: Ch[M,FO](fp16) = A[M,FI] @ W[FI,FO]; plus as/ad dots ============
template<int FI, int FO, bool AF32>
__device__ __forceinline__ void gemm_body(_Float16* blds, int bg,
                                          const void* __restrict__ Av, const float* __restrict__ W,
                                          const float* __restrict__ avs, const float* __restrict__ avd,
                                          __half* __restrict__ Ch, float* __restrict__ as_,
                                          float* __restrict__ ad_, int M){
  constexpr int NT = FO / 16;
  constexpr int KT = FI / 32;
  constexpr int MT = 2;

  int tid = threadIdx.x;
  for (int fl = tid; fl < NT * KT * 64; fl += 256){
    int l = fl & 63, kt = (fl >> 6) % KT, nt = fl / (64 * KT);
    int n = nt * 16 + (l & 15), kb = kt * 32 + (l >> 4) * 8;
    f16x8 v;
    #pragma unroll
    for (int i = 0; i < 8; ++i) v[i] = (_Float16)W[(size_t)(kb + i) * FO + n];
    *(f16x8*)&blds[(size_t)fl * 8] = v;
  }
  __syncthreads();

  int lane = tid & 63, wave = tid >> 6;
  int rbase = lane & 15, kgrp = lane >> 4;
  int r0 = bg * (MT * 16 * 4) + wave * (MT * 16);

  f32x4 c[MT][NT];
  #pragma unroll
  for (int mt = 0; mt < MT; ++mt)
    #pragma unroll
    for (int nt = 0; nt < NT; ++nt)
      c[mt][nt] = (f32x4){0.f, 0.f, 0.f, 0.f};

  for (int kt = 0; kt < KT; ++kt){
    f16x8 a[MT];
    #pragma unroll
    for (int mt = 0; mt < MT; ++mt){
      int arow = min(r0 + mt * 16 + rbase, M - 1);
      if (AF32){
        const float* ap = (const float*)Av + (size_t)arow * FI + kt * 32 + kgrp * 8;
        float4 p0 = *(const float4*)ap;
        float4 p1 = *(const float4*)(ap + 4);
        a[mt][0] = (_Float16)p0.x; a[mt][1] = (_Float16)p0.y;
        a[mt][2] = (_Float16)p0.z; a[mt][3] = (_Float16)p0.w;
        a[mt][4] = (_Float16)p1.x; a[mt][5] = (_Float16)p1.y;
        a[mt][6] = (_Float16)p1.z; a[mt][7] = (_Float16)p1.w;
      } else {
        const __half* ap = (const __half*)Av + (size_t)arow * FI + kt * 32 + kgrp * 8;
        a[mt] = *(const f16x8*)ap;
      }
    }
    #pragma unroll
    for (int nt = 0; nt < NT; ++nt){
      f16x8 b = *(f16x8*)&blds[(size_t)((nt * KT + kt) * 64 + lane) * 8];
      #pragma unroll
      for (int mt = 0; mt < MT; ++mt)
        c[mt][nt] = __builtin_amdgcn_mfma_f32_16x16x32_f16(a[mt], b, c[mt][nt], 0, 0, 0);
    }
  }

  float avs_v[NT], avd_v[NT];
  #pragma unroll
  for (int nt = 0; nt < NT; ++nt){
    avs_v[nt] = avs[nt * 16 + rbase];
    avd_v[nt] = avd[nt * 16 + rbase];
  }
  #pragma unroll
  for (int mt = 0; mt < MT; ++mt){
    #pragma unroll
    for (int i = 0; i < 4; ++i){
      int grow = r0 + mt * 16 + kgrp * 4 + i;
      bool ok = grow < M;
      float s1 = 0.f, s2 = 0.f;
      #pragma unroll
      for (int nt = 0; nt < NT; ++nt){
        float d = c[mt][nt][i];
        if (ok) Ch[(size_t)grow * FO + nt * 16 + rbase] = __float2half(d);
        s1 += d * avs_v[nt];
        s2 += d * avd_v[nt];
      }
      #pragma unroll
      for (int msk = 1; msk <= 8; msk <<= 1){
        s1 += __shfl_xor(s1, msk);
        s2 += __shfl_xor(s2, msk);
      }
      if (ok && rbase == 0){ as_[grow] = s1; ad_[grow] = s2; }
    }
  }
}

// ---- merged dispatch: blocks [0,NBLK1) histogram, blocks [NBLK1, ...) layer-1 GEMM ----
__global__ void k_hist_gemm1(const int* __restrict__ src, const int* __restrict__ dst,
                             int E, int N, int NB, int chunk, int* __restrict__ cnt1,
                             int* __restrict__ done,
                             const float* __restrict__ x, const float* __restrict__ W1,
                             const float* __restrict__ avs, const float* __restrict__ avd,
                             __half* __restrict__ h1, float* __restrict__ as1,
                             float* __restrict__ ad1){
  __shared__ __align__(16) char smem[16384];
  int b = blockIdx.x;
  if (b < NBLK1){
    hist_body((int*)smem, b, src, dst, E, N, NB, chunk, cnt1, done);
  } else {
    gemm_body<D_IN, F1, true>((_Float16*)smem, b - NBLK1, x, W1, avs, avd, h1, as1, ad1, N);
  }
}

// ---- standalone layer-2 GEMM ----
__global__ void k_gemm2(const __half* __restrict__ A, const float* __restrict__ W,
                        const float* __restrict__ avs, const float* __restrict__ avd,
                        __half* __restrict__ Ch, float* __restrict__ as_,
                        float* __restrict__ ad_, int M){
  __shared__ __align__(16) char smem[16384];
  gemm_body<F1, F2, false>((_Float16*)smem, blockIdx.x, A, W, avs, avd, Ch, as_, ad_, M);
}

// per-bucket scan; last block also scans bucket totals, finalizes off[N], zeroes pool/cnt
__global__ void k_colscan(int* __restrict__ cnt1, int* __restrict__ btot,
                          int* __restrict__ done, int NB, int Et,
                          int* __restrict__ bbase, int* __restrict__ off, int N,
                          float* __restrict__ pool, int* __restrict__ cnt){
  __shared__ int lds[256];
  __shared__ int isLast;
  int b = blockIdx.x;
  int t = threadIdx.x;
  int v0 = cnt1[b * NBLK1 + 2 * t], v1 = cnt1[b * NBLK1 + 2 * t + 1];
  int p = v0 + v1;
  lds[t] = p; __syncthreads();
  #pragma unroll
  for (int s = 1; s < 256; s <<= 1){
    int u = (t >= s) ? lds[t - s] : 0;
    __syncthreads(); lds[t] += u; __syncthreads();
  }
  int epre = lds[t] - p;
  cnt1[b * NBLK1 + 2 * t] = epre;
  cnt1[b * NBLK1 + 2 * t + 1] = epre + v0;
  if (t == 255) btot[b] = lds[255];

  __threadfence();
  if (t == 0) isLast = (atomicAdd(done, 1) == (int)gridDim.x - 1);
  __syncthreads();
  if (!isLast) return;
  __threadfence();

  int v = (t < NB) ? btot[t] : 0;
  lds[t] = v; __syncthreads();
  #pragma unroll
  for (int s = 1; s < 256; s <<= 1){
    int u = (t >= s) ? lds[t - s] : 0;
    __syncthreads(); lds[t] += u; __syncthreads();
  }
  if (t < NB) bbase[t] = lds[t] - v;
  if (t == 0){ bbase[NB] = Et; off[N] = Et; }
  for (int i = t; i < NG * F2; i += 256) pool[i] = 0.f;
  if (t < NG) cnt[t] = 0;
}

__global__ void k_scatter1(const int* __restrict__ src, const int* __restrict__ dst,
                           int E, int N, int NB, int chunk,
                           const int* __restrict__ cnt1, const int* __restrict__ bbase,
                           int* __restrict__ tmp){
  __shared__ int cur[256];
  int b = blockIdx.x;
  for (int t = threadIdx.x; t < NB; t += blockDim.x) cur[t] = bbase[t] + cnt1[t * NBLK1 + b];
  __syncthreads();
  int Et = E + N;
  int s0 = b * chunk, s1 = min(s0 + chunk, Et);
  for (int i = s0 + (int)threadIdx.x; i < s1; i += (int)blockDim.x){
    int s, d;
    if (i < E){ s = src[i]; d = dst[i]; } else { s = d = i - E; }
    int bk = d >> 8;
    int p = atomicAdd(&cur[bk], 1);
    tmp[p] = (s << 8) | (d & 255);
  }
}

__global__ void k_sort2(const int* __restrict__ tmp, const int* __restrict__ bbase,
                        int N, int* __restrict__ off, int* __restrict__ csr_src){
  __shared__ int hist[256];
  __shared__ int pre[256];
  int b = blockIdx.x;
  int t = threadIdx.x;
  hist[t] = 0;
  __syncthreads();
  int g0 = bbase[b], g1 = bbase[b + 1];
  for (int i = g0 + t; i < g1; i += 256) atomicAdd(&hist[tmp[i] & 255], 1);
  __syncthreads();
  int v = hist[t];
  pre[t] = v; __syncthreads();
  #pragma unroll
  for (int s = 1; s < 256; s <<= 1){
    int u = (t >= s) ? pre[t - s] : 0;
    __syncthreads(); pre[t] += u; __syncthreads();
  }
  int ex = pre[t] - v;
  int node = (b << 8) + t;
  if (node < N) off[node] = g0 + ex;
  hist[t] = ex;
  __syncthreads();
  for (int i = g0 + t; i < g1; i += 256){
    int e = tmp[i];
    int p = g0 + atomicAdd(&hist[e & 255], 1);
    csr_src[p] = e >> 8;
  }
}

// -------- aggregation: grouped gather + fused weight, 4-deep software pipeline --------
template<int F>
__global__ void k_node(const int* __restrict__ off, const int* __restrict__ csr_src,
                       const float* __restrict__ as_, const float* __restrict__ ad_,
                       const __half* __restrict__ h, const float* __restrict__ bias,
                       __half* __restrict__ outh, int N){
  constexpr int LPR = F / 8;
  constexpr int EPW = 64 / LPR;
  constexpr int U = 4;
  int lane = threadIdx.x & (WAVE - 1);
  int wid = (int)((blockIdx.x * blockDim.x + threadIdx.x) >> 6);
  int node = __builtin_amdgcn_readfirstlane(wid);
  if (node >= N) return;
  int o0 = off[node], o1 = off[node + 1];
  float add = ad_[node];
  int q = lane / LPR;
  int cbase = (lane % LPR) * 8;

  float acc[8];
  #pragma unroll
  for (int i = 0; i < 8; ++i) acc[i] = 0.f;
  float wsum = 0.f;

  for (int jj = o0; jj < o1; jj += U * EPW){
    int s[U]; bool okv[U];
    #pragma unroll
    for (int u = 0; u < U; ++u){
      int j = jj + u * EPW + q;
      okv[u] = j < o1;
      s[u] = csr_src[okv[u] ? j : o0];
    }
    float araw[U];
    #pragma unroll
    for (int u = 0; u < U; ++u) araw[u] = as_[s[u]];
    f16x8 hv[U];
    #pragma unroll
    for (int u = 0; u < U; ++u) hv[u] = *(const f16x8*)(h + (size_t)s[u] * F + cbase);
    #pragma unroll
    for (int u = 0; u < U; ++u){
      float w = okv[u] ? __expf(lrelu(araw[u] + add)) : 0.f;
      wsum += w;
      #pragma unroll
      for (int i = 0; i < 8; ++i) acc[i] += w * (float)hv[u][i];
    }
  }

  #pragma unroll
  for (int m = LPR; m < 64; m <<= 1){
    #pragma unroll
    for (int i = 0; i < 8; ++i) acc[i] += __shfl_xor(acc[i], m);
    wsum += __shfl_xor(wsum, m);
  }

  if (q == 0){
    float inv = 1.f / (wsum + 1e-16f);
    f16x8 o;
    #pragma unroll
    for (int i = 0; i < 8; ++i){
      float v = fmaxf(acc[i] * inv + bias[cbase + i], 0.f);
      o[i] = (_Float16)v;
    }
    *(f16x8*)(outh + (size_t)node * F + cbase) = o;
  }
}

// ---------------- pooling (batch sorted): strip reduction, few atomics ----------------
__global__ void k_pool(const __half* __restrict__ h, const int* __restrict__ batch,
                       float* __restrict__ pool, int* __restrict__ cnt, int N, int strip){
  int f = threadIdx.x;  // 0..127
  int n0 = blockIdx.x * strip;
  if (n0 >= N) return;
  int n1 = min(n0 + strip, N);
  int g = batch[n0];
  float acc = 0.f;
  int c = 0;
  for (int n = n0; n < n1; ++n){
    int gn = batch[n];
    if (gn != g){
      atomicAdd(&pool[g * F2 + f], acc);
      if (f == 0) atomicAdd(&cnt[g], c);
      acc = 0.f; c = 0; g = gn;
    }
    acc += __half2float(h[(size_t)n * F2 + f]);
    c++;
  }
  atomicAdd(&pool[g * F2 + f], acc);
  if (f == 0) atomicAdd(&cnt[g], c);
}

// ---------------- final FC ----------------
__global__ void k_fc(const float* __restrict__ pool, const int* __restrict__ cnt,
                     const float* __restrict__ Wfc, const float* __restrict__ bfc,
                     float* __restrict__ out){
  int g = blockIdx.x, o = threadIdx.x;  // 64 x 64
  __shared__ float p[F2];
  float invc = 1.f / fmaxf((float)cnt[g], 1.f);
  for (int k = threadIdx.x; k < F2; k += 64) p[k] = pool[g * F2 + k] * invc;
  __syncthreads();
  float acc = bfc[o];
  for (int k = 0; k < F2; ++k) acc += p[k] * Wfc[k * 64 + o];
  out[g * 64 + o] = acc;
}

extern "C" void kernel_launch(void* const* d_in, const int* in_sizes, int n_in,
                              void* d_out, int out_size, void* d_ws, size_t ws_size,
                              hipStream_t stream){
  const float* x    = (const float*)d_in[0];
  const int*   edge = (const int*)d_in[1];
  const int*   batch= (const int*)d_in[2];
  const float* W1   = (const float*)d_in[3];
  const float* av_s1= (const float*)d_in[4];
  const float* av_d1= (const float*)d_in[5];
  const float* b1   = (const float*)d_in[6];
  const float* W2   = (const float*)d_in[7];
  const float* av_s2= (const float*)d_in[8];
  const float* av_d2= (const float*)d_in[9];
  const float* b2   = (const float*)d_in[10];
  const float* Wfc  = (const float*)d_in[11];
  const float* bfc  = (const float*)d_in[12];
  float* out = (float*)d_out;

  const int N  = in_sizes[2];
  const int E  = in_sizes[1] / 2;
  const int Et = E + N;
  const int NB = (N + 255) >> 8;
  const int* src = edge;
  const int* dst = edge + E;

  char* p = (char*)d_ws;
  auto alloc = [&](size_t bytes)->void*{
    void* r = (void*)p;
    p += (bytes + 255) & ~(size_t)255;
    return r;
  };
  __half* h1  = (__half*)alloc((size_t)N * F1 * 2);
  __half* h1r = (__half*)alloc((size_t)N * F1 * 2);
  __half* h2  = (__half*)alloc((size_t)N * F2 * 2);
  __half* h2r = (__half*)alloc((size_t)N * F2 * 2);
  float* as1  = (float*)alloc((size_t)N * 4);
  float* ad1  = (float*)alloc((size_t)N * 4);
  float* as2  = (float*)alloc((size_t)N * 4);
  float* ad2  = (float*)alloc((size_t)N * 4);
  float* pool = (float*)alloc((size_t)NG * F2 * 4);
  int* off    = (int*)alloc((size_t)(N + 1) * 4);
  int* csr_src= (int*)alloc((size_t)Et * 4);
  int* tmp    = (int*)alloc((size_t)Et * 4);
  int* cnt1   = (int*)alloc((size_t)256 * NBLK1 * 4);
  int* btot   = (int*)alloc((size_t)256 * 4);
  int* bbase  = (int*)alloc((size_t)257 * 4);
  int* cnt    = (int*)alloc((size_t)NG * 4);
  int* done   = (int*)alloc((size_t)256 * 4);

  int chunk = (Et + NBLK1 - 1) / NBLK1;
  int gemm_blocks = (N + 127) / 128;
  int node_blocks = (N + 3) / 4;   // 4 waves (nodes) per 256-thread block

  // [hist ∥ layer-1 GEMM] -> colscan(+bucketscan+zero) -> scatter1 -> sort2
  k_hist_gemm1<<<NBLK1 + gemm_blocks, 256, 0, stream>>>(src, dst, E, N, NB, chunk, cnt1, done,
                                                        x, W1, av_s1, av_d1, h1, as1, ad1);
  k_colscan<<<NB, 256, 0, stream>>>(cnt1, btot, done, NB, Et, bbase, off, N, pool, cnt);
  k_scatter1<<<NBLK1, 256, 0, stream>>>(src, dst, E, N, NB, chunk, cnt1, bbase, tmp);
  k_sort2<<<NB, 256, 0, stream>>>(tmp, bbase, N, off, csr_src);

  // layer 1 aggregation
  k_node<F1><<<node_blocks, 256, 0, stream>>>(off, csr_src, as1, ad1, h1, b1, h1r, N);

  // layer 2
  k_gemm2<<<gemm_blocks, 256, 0, stream>>>(h1r, W2, av_s2, av_d2, h2, as2, ad2, N);
  k_node<F2><<<node_blocks, 256, 0, stream>>>(off, csr_src, as2, ad2, h2, b2, h2r, N);

  // pooling + FC
  int strip = 128;
  int pool_blocks = (N + strip - 1) / strip;
  k_pool<<<pool_blocks, F2, 0, stream>>>(h2r, batch, pool, cnt, N, strip);
  k_fc<<<NG, 64, 0, stream>>>(pool, cnt, Wfc, bfc, out);
}